// Round 21
// baseline (189.462 us; speedup 1.0000x reference)
//
#include <hip/hip_runtime.h>

// TransformerDecoderLayer: B=4,S=2048,D=512,H=8,DK=64,DFF=2048, fp32 in/out.
// R21 = R20 (165.4us) with ONE change: SPLIT=1 (512-thr split-K, 2 blocks/CU,
// 16 waves/CU vs 12) extended to gemm<0> (QKV) and gemm<2> (FF1) - the R19
// lever applied to the remaining 256-thr GEMMs. attn/prep/LN byte-identical.

typedef __bf16 bf16x8 __attribute__((ext_vector_type(8)));
typedef float f32x4 __attribute__((ext_vector_type(4)));
typedef unsigned short us4 __attribute__((ext_vector_type(4)));
typedef unsigned u32x4 __attribute__((ext_vector_type(4)));

__device__ __forceinline__ unsigned short f2bf(float f){
  unsigned u = __builtin_bit_cast(unsigned, f);
  u += 0x7fffu + ((u >> 16) & 1u);   // RNE
  return (unsigned short)(u >> 16);
}
__device__ __forceinline__ float bf2f(unsigned short s){
  return __builtin_bit_cast(float, (unsigned)s << 16);
}

__device__ __forceinline__ unsigned cvt_pk_bf16(float lo, float hi){
  unsigned r;
  asm("v_cvt_pk_bf16_f32 %0, %1, %2" : "=v"(r) : "v"(lo), "v"(hi));
  return r;
}
__device__ __forceinline__ void plswap32(unsigned &a, unsigned &b){
  asm volatile("v_permlane32_swap_b32 %0, %1" : "+v"(a), "+v"(b));
}
__device__ __forceinline__ void plswap16(unsigned &a, unsigned &b){
  asm volatile("v_permlane16_swap_b32 %0, %1" : "+v"(a), "+v"(b));
}
__device__ __forceinline__ float exp2_hw(float x){   // D = 2^S0, single HW op
  float r;
  asm("v_exp_f32 %0, %1" : "=v"(r) : "v"(x));
  return r;
}

typedef const __attribute__((address_space(1))) void* gas_t;
typedef __attribute__((address_space(3))) void* las_t;
__device__ __forceinline__ void gl_lds16(const void* g, void* l){
  __builtin_amdgcn_global_load_lds((gas_t)g, (las_t)l, 16, 0, 0);
}

// ---------- mega-prep: all input conversions in one kernel ----------
struct PrepSh { float t[32][33]; unsigned red[4]; };

__device__ __forceinline__ void wtrans_body(const float* __restrict__ in,
    unsigned short* __restrict__ out, int K, int N, int k0, int n0, int tid,
    float (*t)[33]){
  int tx = tid & 31, ty = tid >> 5;
  #pragma unroll
  for (int r = 0; r < 4; ++r)
    t[ty + 8*r][tx] = in[(size_t)(k0 + ty + 8*r)*N + n0 + tx];
  __syncthreads();
  #pragma unroll
  for (int r = 0; r < 4; ++r)
    out[(size_t)(n0 + ty + 8*r)*K + k0 + tx] = f2bf(t[tx][ty + 8*r]);
}

__global__ __launch_bounds__(256) void k_prep(
    const int* __restrict__ mask, const float* __restrict__ src,
    const float* __restrict__ qw, const float* __restrict__ kw, const float* __restrict__ vw,
    const float* __restrict__ qb, const float* __restrict__ kb, const float* __restrict__ vb,
    const float* __restrict__ ow, const float* __restrict__ w1, const float* __restrict__ w2,
    unsigned short* __restrict__ mb16, unsigned short* __restrict__ x_bf,
    unsigned short* __restrict__ wtqkv, float* __restrict__ bqkv,
    unsigned short* __restrict__ wto, unsigned short* __restrict__ wt1,
    unsigned short* __restrict__ wt2)
{
  __shared__ PrepSh sh;
  const int tid = threadIdx.x;
  int id = blockIdx.x;
  if (id < 256){
    const int bq = id & 127, half = id >> 7;
    const int b = bq >> 5, qt = bq & 31;
    const int* base = mask + (size_t)b*2048*2048 + (size_t)(qt*64 + (tid>>4)*4)*2048 + (tid&15)*4;
    unsigned bits = 0;
    for (int i = 0; i < 16; ++i){
      const int* p = base + (half*16 + i)*64;
      int ok = 1;
      #pragma unroll
      for (int r = 0; r < 4; ++r){
        int4 v = *reinterpret_cast<const int4*>(p + (size_t)r*2048);
        ok &= (v.x!=0)&(v.y!=0)&(v.z!=0)&(v.w!=0);
      }
      bits |= (unsigned)ok << i;
    }
    #pragma unroll
    for (int o = 1; o < 64; o <<= 1) bits &= __shfl_xor(bits, o);
    if ((tid & 63) == 0) sh.red[tid >> 6] = bits;
    __syncthreads();
    if (tid == 0) mb16[bq*2 + half] = (unsigned short)(sh.red[0]&sh.red[1]&sh.red[2]&sh.red[3]);
    return;
  }
  id -= 256;
  if (id < 4096){
    int i = id * 256 + tid;
    float4 v = reinterpret_cast<const float4*>(src)[i];
    us4 o = { f2bf(v.x), f2bf(v.y), f2bf(v.z), f2bf(v.w) };
    reinterpret_cast<us4*>(x_bf)[i] = o;
    return;
  }
  id -= 4096;
  if (id < 768){
    int z = id / 32, rem = id % 32, x = rem & 15, y = rem >> 4;
    int sel = z >> 3, h = z & 7;
    const float* in = (sel==0 ? qw : (sel==1 ? kw : vw)) + (size_t)h*512*64;
    unsigned short* o = wtqkv + ((size_t)(sel*512 + h*64)) * 512;
    wtrans_body(in, o, 512, 64, x*32, y*32, tid, sh.t);
    return;
  }
  id -= 768;
  if (id < 6){
    int n = id*256 + tid;
    if (n < 1536){ int sel = n >> 9, r = n & 511;
      bqkv[n] = (sel==0 ? qb : (sel==1 ? kb : vb))[r]; }
    return;
  }
  id -= 6;
  if (id < 256){
    wtrans_body(ow, wto, 512, 512, (id & 15)*32, (id >> 4)*32, tid, sh.t);
    return;
  }
  id -= 256;
  if (id < 1024){
    wtrans_body(w1, wt1, 512, 2048, (id & 15)*32, (id >> 4)*32, tid, sh.t);
    return;
  }
  id -= 1024;
  wtrans_body(w2, wt2, 2048, 512, (id & 63)*32, (id >> 6)*32, tid, sh.t);
}

// ---------- GEMM: BK=64, per-row XOR swizzle; SPLIT=1 -> split-K in block ----------
// SPLIT=1: 512 thr / 8 waves; waves 0-3 K-half 0, waves 4-7 K-half 1; LDS-reduce.
// MODE 0: QKV scatter; 1: of = acc+bias+resid(f32); 2: ob0 = bf16 relu;
// MODE 3: of = acc+bias+bf2f(ob1[resid])
template<int MODE, int SPLIT>
__global__ __launch_bounds__(SPLIT ? 512 : 256, SPLIT ? 2 : 3) void k_gemm(
    const unsigned short* __restrict__ A, const unsigned short* __restrict__ Bt,
    const float* __restrict__ bias, const float* __restrict__ resid,
    unsigned short* __restrict__ ob0, const unsigned short* __restrict__ ob1,
    unsigned short* __restrict__ ob2,
    float* __restrict__ of, int M, int N, int K)
{
  constexpr int NG = SPLIT ? 2 : 1;
  __shared__ unsigned short As[NG][128*64];
  __shared__ unsigned short Bs[NG][128*64];
  const int tid = threadIdx.x, lane = tid & 63, wid = tid >> 6;
  const int w4 = wid & 3, kh = SPLIT ? (wid >> 2) : 0;
  const int g = lane >> 4, lr = lane & 15;
  const int rowBase = blockIdx.x * 128, colBase = blockIdx.y * 128;
  const int wr = (w4 >> 1) * 64, wc = (w4 & 1) * 64;
  const int srow8 = lane >> 3;
  const int schunk = (lane & 7) ^ (srow8 & 7);
  const int Keff = SPLIT ? (K >> 1) : K;
  const unsigned short* pA = A + (size_t)(rowBase + w4*32 + srow8)*K + kh*Keff + schunk*8;
  const unsigned short* pB = Bt + (size_t)(colBase + w4*32 + srow8)*K + kh*Keff + schunk*8;
  f32x4 acc[4][4] = {};
  for (int k0 = 0; k0 < Keff; k0 += 64){
    __syncthreads();
    #pragma unroll
    for (int t = 0; t < 4; ++t){
      gl_lds16(pA + (size_t)(t*8)*K + k0, &As[kh][(w4*32 + t*8)*64]);
      gl_lds16(pB + (size_t)(t*8)*K + k0, &Bs[kh][(w4*32 + t*8)*64]);
    }
    __syncthreads();
    #pragma unroll
    for (int ks = 0; ks < 2; ++ks){
      const int rc = ((ks*4 + g) ^ (lr & 7)) * 8;
      bf16x8 af[4], bfr[4];
      #pragma unroll
      for (int mi = 0; mi < 4; ++mi) af[mi]  = *reinterpret_cast<const bf16x8*>(&As[kh][(wr + mi*16 + lr)*64 + rc]);
      #pragma unroll
      for (int ni = 0; ni < 4; ++ni) bfr[ni] = *reinterpret_cast<const bf16x8*>(&Bs[kh][(wc + ni*16 + lr)*64 + rc]);
      __builtin_amdgcn_s_setprio(1);
      #pragma unroll
      for (int mi = 0; mi < 4; ++mi)
        #pragma unroll
        for (int ni = 0; ni < 4; ++ni)
          acc[mi][ni] = __builtin_amdgcn_mfma_f32_16x16x32_bf16(af[mi], bfr[ni], acc[mi][ni], 0, 0, 0);
      __builtin_amdgcn_s_setprio(0);
    }
  }
  if constexpr (SPLIT){
    // cross-group reduce: high wave w+4's acc added into low wave w's acc.
    float* xb = (float*)&As[0][0];
    #pragma unroll
    for (int p = 0; p < 2; ++p){
      __syncthreads();
      if (kh == 1 && (w4 >> 1) == p){
        const int slot = w4 & 1;
        #pragma unroll
        for (int mi = 0; mi < 4; ++mi)
          #pragma unroll
          for (int ni = 0; ni < 4; ++ni)
            #pragma unroll
            for (int j = 0; j < 4; ++j)
              xb[slot*4096 + (mi*16 + ni*4 + j)*64 + lane] = acc[mi][ni][j];
      }
      __syncthreads();
      if (kh == 0 && (w4 >> 1) == p){
        const int slot = w4 & 1;
        #pragma unroll
        for (int mi = 0; mi < 4; ++mi)
          #pragma unroll
          for (int ni = 0; ni < 4; ++ni)
            #pragma unroll
            for (int j = 0; j < 4; ++j)
              acc[mi][ni][j] += xb[slot*4096 + (mi*16 + ni*4 + j)*64 + lane];
      }
    }
    if (kh == 1) return;   // high waves done (no barriers after this point)
  }
  float bv[4];
  #pragma unroll
  for (int ni = 0; ni < 4; ++ni) bv[ni] = bias[colBase + wc + ni*16 + lr];
  #pragma unroll
  for (int mi = 0; mi < 4; ++mi){
    #pragma unroll
    for (int ni = 0; ni < 4; ++ni){
      #pragma unroll
      for (int j = 0; j < 4; ++j){
        int m = rowBase + wr + mi*16 + g*4 + j;
        int n = colBase + wc + ni*16 + lr;
        float v = acc[mi][ni][j] + bv[ni];
        if constexpr (MODE == 0){
          int b = m >> 11, s = m & 2047;
          int sel = n >> 9, rr = n & 511, h = rr >> 6, e = rr & 63;
          size_t bh = (size_t)(b*8 + h);
          if (sel == 0)      ob0[(bh*2048 + s)*64 + e] = f2bf(v);
          else if (sel == 1) ((unsigned short*)ob1)[(bh*2048 + s)*64 + e] = f2bf(v);
          else               ob2[(bh*64 + e)*2048 + s] = f2bf(v);   // V transposed
        } else if constexpr (MODE == 1){
          of[(size_t)m*N + n] = v + resid[(size_t)m*N + n];
        } else if constexpr (MODE == 3){
          of[(size_t)m*N + n] = v + bf2f(ob1[(size_t)m*N + n]);
        } else {
          ob0[(size_t)m*N + n] = f2bf(v > 0.f ? v : 0.f);
        }
      }
    }
  }
}

// ---------- flash attention (R20-identical): KVBLK=128, 16 q/wave, 8 waves; MFMA l-sum ----------
__global__ __launch_bounds__(512) void k_attn(
    const unsigned short* __restrict__ Qb, const unsigned short* __restrict__ Kb,
    const unsigned short* __restrict__ Vt, const int* __restrict__ mask,
    const unsigned* __restrict__ mbits_p, unsigned short* __restrict__ ctx)
{
  __shared__ unsigned short Ks[2][8192];   // 128 x 64
  __shared__ unsigned short Vs[2][8192];   // 64 x 128
  const int tid = threadIdx.x, lane = tid & 63, wid = tid >> 6;   // wid 0..7
  const int g = lane >> 4, lr = lane & 15;
  const int qt = blockIdx.y, bh = blockIdx.x;   // bh fastest -> XCD locality
  const int b = bh >> 3, h = bh & 7;
  const int qw = qt * 128 + wid * 16;
  const unsigned mbits = mbits_p[b*32 + qt*2] & mbits_p[b*32 + qt*2 + 1];
  const size_t mbase = (size_t)b * 2048 * 2048;
  const float SC = 0.18033688f;   // log2(e)/sqrt(64)

  const int l8 = lane >> 3, l7 = lane & 7, l16 = lane >> 4, l15 = lane & 15;
  const unsigned short* kg0 = Kb + (size_t)bh*2048*64 + ((size_t)(wid*16) + l8)*64 + ((l7 ^ (l8 & 7)))*8;
  const int vrow0 = wid*8 + l16, vrow1 = wid*8 + 4 + l16;
  const unsigned short* vg0 = Vt + (size_t)bh*64*2048 + (size_t)vrow0*2048 + ((l15 ^ (vrow0 & 15)))*8;
  const unsigned short* vg1 = Vt + (size_t)bh*64*2048 + (size_t)vrow1*2048 + ((l15 ^ (vrow1 & 15)))*8;

  #define STAGE(buf, t) do { \
    gl_lds16(kg0 + (size_t)(t)*8192,       &Ks[buf][(wid*16)*64]);    \
    gl_lds16(kg0 + (size_t)(t)*8192 + 512, &Ks[buf][(wid*16+8)*64]);  \
    gl_lds16(vg0 + (size_t)(t)*128,        &Vs[buf][(wid*8)*128]);    \
    gl_lds16(vg1 + (size_t)(t)*128,        &Vs[buf][(wid*8+4)*128]);  \
  } while(0)

  STAGE(0, 0);

  bf16x8 b_q[2];   // Q as B-operand: col q = lr, k(e) = ks*32 + 8g + j
  {
    const unsigned short* qp = Qb + ((size_t)bh*2048 + qw + lr)*64;
    b_q[0] = *reinterpret_cast<const bf16x8*>(qp + g*8);
    b_q[1] = *reinterpret_cast<const bf16x8*>(qp + 32 + g*8);
  }
  const u32x4 ones_u = { 0x3f803f80u, 0x3f803f80u, 0x3f803f80u, 0x3f803f80u };
  const bf16x8 ones = __builtin_bit_cast(bf16x8, ones_u);   // all bf16 1.0
  f32x4 acc[4] = {};    // ctx^T frags: row e = ne*16+4g+j, col q = lr
  f32x4 acc_l = {};     // ones x P: every row = l partial for col q = lr
  float m_run = -3.0e38f;
  int cur = 0;
  __syncthreads();     // first tile staged (vmcnt drained by barrier semantics)

  for (int kt = 0; kt < 16; ++kt){
    if (kt < 15) STAGE(cur^1, kt+1);   // issue next-tile DMA; lands before end barrier
    const unsigned short* Kc = Ks[cur];
    const unsigned short* Vc = Vs[cur];
    // QK^T (swapped): A = K rows (k = mk*16+4g+j), B = Q (col q = lr)
    f32x4 st[8];
    #pragma unroll
    for (int mk = 0; mk < 8; ++mk) st[mk] = f32x4{0.f,0.f,0.f,0.f};
    __builtin_amdgcn_s_setprio(1);
    #pragma unroll
    for (int mk = 0; mk < 8; ++mk)
      #pragma unroll
      for (int ks = 0; ks < 2; ++ks){
        bf16x8 kf = *reinterpret_cast<const bf16x8*>(
            &Kc[(mk*16 + lr)*64 + (((ks*4 + g) ^ (lr & 7)))*8]);
        st[mk] = __builtin_amdgcn_mfma_f32_16x16x32_bf16(kf, b_q[ks], st[mk], 0,0,0);
      }
    __builtin_amdgcn_s_setprio(0);
    if (((mbits >> (kt*2)) & 3u) != 3u){
      const int kk0 = kt * 128;
      #pragma unroll
      for (int mk = 0; mk < 8; ++mk)
        #pragma unroll
        for (int j = 0; j < 4; ++j){
          int kg = kk0 + mk*16 + g*4 + j;
          if (mask[mbase + (size_t)(qw + lr)*2048 + kg] == 0) st[mk][j] = -3.0e30f;
        }
    }
    // online softmax (log2 domain); max tree over 32 values
    float pm[8];
    #pragma unroll
    for (int mk = 0; mk < 8; ++mk)
      pm[mk] = fmaxf(fmaxf(st[mk][0], st[mk][1]), fmaxf(st[mk][2], st[mk][3]));
    float tA = fmaxf(fmaxf(pm[0], pm[1]), fmaxf(pm[2], pm[3]));
    float tB = fmaxf(fmaxf(pm[4], pm[5]), fmaxf(pm[6], pm[7]));
    float tm = fmaxf(tA, tB);
    tm = fmaxf(tm, __shfl_xor(tm, 16));
    tm = fmaxf(tm, __shfl_xor(tm, 32));
    float tms = tm * SC;
    if (!__all(tms <= m_run + 8.f)){   // defer-max, THR=8 (P bounded by 2^8)
      float mnew = fmaxf(m_run, tms);
      float alpha = exp2_hw(m_run - mnew);
      #pragma unroll
      for (int ne = 0; ne < 4; ++ne)
        #pragma unroll
        for (int j = 0; j < 4; ++j) acc[ne][j] *= alpha;
      #pragma unroll
      for (int j = 0; j < 4; ++j) acc_l[j] *= alpha;
      m_run = mnew;
    }
    // P = 2^(S*SC - m_run); pack bf16; permlane -> PV B-frags
    unsigned wrd[8][2];
    #pragma unroll
    for (int mk = 0; mk < 8; ++mk){
      float p0 = exp2_hw(__builtin_fmaf(st[mk][0], SC, -m_run));
      float p1 = exp2_hw(__builtin_fmaf(st[mk][1], SC, -m_run));
      float p2 = exp2_hw(__builtin_fmaf(st[mk][2], SC, -m_run));
      float p3 = exp2_hw(__builtin_fmaf(st[mk][3], SC, -m_run));
      wrd[mk][0] = cvt_pk_bf16(p0, p1);
      wrd[mk][1] = cvt_pk_bf16(p2, p3);
    }
    bf16x8 pw[4];
    #pragma unroll
    for (int ks = 0; ks < 4; ++ks){
      unsigned a0w = wrd[2*ks][0], b0w = wrd[2*ks+1][0];
      unsigned a1w = wrd[2*ks][1], b1w = wrd[2*ks+1][1];
      plswap32(a0w, b0w); plswap16(a0w, b0w);
      plswap32(a1w, b1w); plswap16(a1w, b1w);
      u32x4 pk = { a0w, a1w, b0w, b1w };
      pw[ks] = __builtin_bit_cast(bf16x8, pk);
    }
    // PV: ctx^T += Vt * P^T ; l += ones * P^T (matrix pipe computes the denom)
    __builtin_amdgcn_s_setprio(1);
    #pragma unroll
    for (int ks = 0; ks < 4; ++ks){
      #pragma unroll
      for (int ne = 0; ne < 4; ++ne){
        bf16x8 vf = *reinterpret_cast<const bf16x8*>(
            &Vc[(ne*16 + lr)*128 + (((ks*4 + g) ^ lr))*8]);
        acc[ne] = __builtin_amdgcn_mfma_f32_16x16x32_bf16(vf, pw[ks], acc[ne], 0,0,0);
      }
      acc_l = __builtin_amdgcn_mfma_f32_16x16x32_bf16(ones, pw[ks], acc_l, 0,0,0);
    }
    __builtin_amdgcn_s_setprio(0);
    if (kt < 15){
      __syncthreads();   // drains next-tile DMA + orders buffer reuse
      cur ^= 1;
    }
  }
  #undef STAGE
  float inv = 1.f / acc_l[0];   // all rows of ones x P are identical
  int q = qw + lr;
  #pragma unroll
  for (int ne = 0; ne < 4; ++ne){
    uint2 ow;
    ow.x = cvt_pk_bf16(acc[ne][0]*inv, acc[ne][1]*inv);
    ow.y = cvt_pk_bf16(acc[ne][2]*inv, acc[ne][3]*inv);
    *reinterpret_cast<uint2*>(&ctx[((size_t)b*2048 + q)*512 + h*64 + ne*16 + g*4]) = ow;
  }
}

// ---------- LayerNorm: wave per row of 512; f32 out optional ----------
__global__ __launch_bounds__(256) void k_ln(
    const float* __restrict__ in, const float* __restrict__ gma, const float* __restrict__ bta,
    float* __restrict__ of, unsigned short* __restrict__ ob)
{
  const int lane = threadIdx.x & 63, wid = threadIdx.x >> 6;
  const size_t row = (size_t)blockIdx.x * 4 + wid;
  const float* x = in + row * 512;
  const int e0 = lane * 8;
  float xv[8];
  *reinterpret_cast<float4*>(&xv[0]) = *reinterpret_cast<const float4*>(x + e0);
  *reinterpret_cast<float4*>(&xv[4]) = *reinterpret_cast<const float4*>(x + e0 + 4);
  float s = 0.f, ss = 0.f;
  #pragma unroll
  for (int i = 0; i < 8; ++i){ s += xv[i]; ss += xv[i]*xv[i]; }
  #pragma unroll
  for (int o = 1; o < 64; o <<= 1){ s += __shfl_xor(s, o); ss += __shfl_xor(ss, o); }
  float mu = s * (1.f/512.f);
  float var = ss * (1.f/512.f) - mu*mu;
  float rs = rsqrtf(var + 1e-5f);
  float gv[8], bv[8], y[8];
  *reinterpret_cast<float4*>(&gv[0]) = *reinterpret_cast<const float4*>(gma + e0);
  *reinterpret_cast<float4*>(&gv[4]) = *reinterpret_cast<const float4*>(gma + e0 + 4);
  *reinterpret_cast<float4*>(&bv[0]) = *reinterpret_cast<const float4*>(bta + e0);
  *reinterpret_cast<float4*>(&bv[4]) = *reinterpret_cast<const float4*>(bta + e0 + 4);
  #pragma unroll
  for (int i = 0; i < 8; ++i) y[i] = (xv[i]-mu)*rs*gv[i] + bv[i];
  if (of){
    *reinterpret_cast<float4*>(of + row*512 + e0)     = *reinterpret_cast<float4*>(&y[0]);
    *reinterpret_cast<float4*>(of + row*512 + e0 + 4) = *reinterpret_cast<float4*>(&y[4]);
  }
  if (ob){
    us4 o0 = { f2bf(y[0]), f2bf(y[1]), f2bf(y[2]), f2bf(y[3]) };
    us4 o1 = { f2bf(y[4]), f2bf(y[5]), f2bf(y[6]), f2bf(y[7]) };
    *reinterpret_cast<us4*>(ob + row*512 + e0)     = o0;
    *reinterpret_cast<us4*>(ob + row*512 + e0 + 4) = o1;
  }
}

extern "C" void kernel_launch(void* const* d_in, const int* in_sizes, int n_in,
                              void* d_out, int out_size, void* d_ws, size_t ws_size,
                              hipStream_t stream)
{
  const float* src  = (const float*)d_in[0];
  const int*   mask = (const int*)d_in[1];
  const float* q_w  = (const float*)d_in[2];
  const float* q_b  = (const float*)d_in[3];
  const float* k_w  = (const float*)d_in[4];
  const float* k_b  = (const float*)d_in[5];
  const float* v_w  = (const float*)d_in[6];
  const float* v_b  = (const float*)d_in[7];
  const float* o_w  = (const float*)d_in[8];
  const float* o_b  = (const float*)d_in[9];
  const float* ln1g = (const float*)d_in[10];
  const float* ln1b = (const float*)d_in[11];
  const float* w1   = (const float*)d_in[12];
  const float* b1   = (const float*)d_in[13];
  const float* w2   = (const float*)d_in[14];
  const float* b2   = (const float*)d_in[15];
  const float* ln2g = (const float*)d_in[16];
  const float* ln2b = (const float*)d_in[17];

  char* ws = (char*)d_ws;
  if (ws_size < 81795072) return;
  unsigned short* x_bf  = (unsigned short*)(ws + 0);          // 8.4MB (reused as LN1 bf16 out)
  unsigned short* wtqkv = (unsigned short*)(ws + 8388608);
  float*          bqkv  = (float*)(ws + 9961472);
  unsigned short* wto   = (unsigned short*)(ws + 9967616);
  unsigned short* wt1   = (unsigned short*)(ws + 10491904);
  unsigned short* wt2   = (unsigned short*)(ws + 12589056);
  unsigned short* Qb    = (unsigned short*)(ws + 14686208);
  unsigned short* Kb    = (unsigned short*)(ws + 23074816);
  unsigned short* Vt    = (unsigned short*)(ws + 31463424);
  unsigned short* ctx   = (unsigned short*)(ws + 39852032);
  unsigned short* ffb   = (unsigned short*)(ws + 14686208);   // overlays Q/K/Vt/ctx (dead by FF1)
  float* res = (float*)(ws + 48240640);                        // res1 then res2
  unsigned short* mb16 = (unsigned short*)(ws + 48240640);     // bitmap in res head (dead by gemm<1>)
  const unsigned* mb32 = (const unsigned*)(ws + 48240640);
  float* outf = (float*)d_out;

  k_prep<<<7430, 256, 0, stream>>>(mask, src, q_w, k_w, v_w, q_b, k_b, v_b,
                                   o_w, w1, w2, mb16, x_bf, wtqkv, bqkv, wto, wt1, wt2);

  k_gemm<0,1><<<dim3(64,12), 512, 0, stream>>>(x_bf, wtqkv, bqkv, nullptr,
                                               Qb, Kb, Vt, nullptr, 8192, 1536, 512);
  k_attn<<<dim3(32,16), 512, 0, stream>>>(Qb, Kb, Vt, mask, mb32, ctx);
  k_gemm<1,1><<<dim3(64,4), 512, 0, stream>>>(ctx, wto, o_b, src,
                                              nullptr, nullptr, nullptr, res, 8192, 512, 512);
  k_ln<<<2048, 256, 0, stream>>>(res, ln1g, ln1b, nullptr, x_bf);   // bf16 only
  k_gemm<2,1><<<dim3(64,16), 512, 0, stream>>>(x_bf, wt1, b1, nullptr,
                                               ffb, nullptr, nullptr, nullptr, 8192, 2048, 512);
  k_gemm<3,1><<<dim3(64,4), 512, 0, stream>>>(ffb, wt2, b2, nullptr,
                                              nullptr, x_bf, nullptr, res, 8192, 512, 2048);
  k_ln<<<2048, 256, 0, stream>>>(res, ln2g, ln2b, outf, nullptr);
}

// Round 22
// 165.114 us; speedup vs baseline: 1.1475x; 1.1475x over previous
//
#include <hip/hip_runtime.h>

// TransformerDecoderLayer: B=4,S=2048,D=512,H=8,DK=64,DFF=2048, fp32 in/out.
// R22 = exact revert to R20 champion (165.4us). R21's SPLIT-everywhere regressed
// (grid fragmentation: 768-block gemm<0> went from 1.0 to 1.5 scheduling passes).
// Config: gemm<0>/<2> 256-thr 3-blocks/CU; gemm<1>/<3> 512-thr split-K;
// attn KVBLK=128 + exp2_hw + MFMA l-sum; mega-prep; bf16 LN1 residual.

typedef __bf16 bf16x8 __attribute__((ext_vector_type(8)));
typedef float f32x4 __attribute__((ext_vector_type(4)));
typedef unsigned short us4 __attribute__((ext_vector_type(4)));
typedef unsigned u32x4 __attribute__((ext_vector_type(4)));

__device__ __forceinline__ unsigned short f2bf(float f){
  unsigned u = __builtin_bit_cast(unsigned, f);
  u += 0x7fffu + ((u >> 16) & 1u);   // RNE
  return (unsigned short)(u >> 16);
}
__device__ __forceinline__ float bf2f(unsigned short s){
  return __builtin_bit_cast(float, (unsigned)s << 16);
}

__device__ __forceinline__ unsigned cvt_pk_bf16(float lo, float hi){
  unsigned r;
  asm("v_cvt_pk_bf16_f32 %0, %1, %2" : "=v"(r) : "v"(lo), "v"(hi));
  return r;
}
__device__ __forceinline__ void plswap32(unsigned &a, unsigned &b){
  asm volatile("v_permlane32_swap_b32 %0, %1" : "+v"(a), "+v"(b));
}
__device__ __forceinline__ void plswap16(unsigned &a, unsigned &b){
  asm volatile("v_permlane16_swap_b32 %0, %1" : "+v"(a), "+v"(b));
}
__device__ __forceinline__ float exp2_hw(float x){   // D = 2^S0, single HW op
  float r;
  asm("v_exp_f32 %0, %1" : "=v"(r) : "v"(x));
  return r;
}

typedef const __attribute__((address_space(1))) void* gas_t;
typedef __attribute__((address_space(3))) void* las_t;
__device__ __forceinline__ void gl_lds16(const void* g, void* l){
  __builtin_amdgcn_global_load_lds((gas_t)g, (las_t)l, 16, 0, 0);
}

// ---------- mega-prep: all input conversions in one kernel ----------
struct PrepSh { float t[32][33]; unsigned red[4]; };

__device__ __forceinline__ void wtrans_body(const float* __restrict__ in,
    unsigned short* __restrict__ out, int K, int N, int k0, int n0, int tid,
    float (*t)[33]){
  int tx = tid & 31, ty = tid >> 5;
  #pragma unroll
  for (int r = 0; r < 4; ++r)
    t[ty + 8*r][tx] = in[(size_t)(k0 + ty + 8*r)*N + n0 + tx];
  __syncthreads();
  #pragma unroll
  for (int r = 0; r < 4; ++r)
    out[(size_t)(n0 + ty + 8*r)*K + k0 + tx] = f2bf(t[tx][ty + 8*r]);
}

__global__ __launch_bounds__(256) void k_prep(
    const int* __restrict__ mask, const float* __restrict__ src,
    const float* __restrict__ qw, const float* __restrict__ kw, const float* __restrict__ vw,
    const float* __restrict__ qb, const float* __restrict__ kb, const float* __restrict__ vb,
    const float* __restrict__ ow, const float* __restrict__ w1, const float* __restrict__ w2,
    unsigned short* __restrict__ mb16, unsigned short* __restrict__ x_bf,
    unsigned short* __restrict__ wtqkv, float* __restrict__ bqkv,
    unsigned short* __restrict__ wto, unsigned short* __restrict__ wt1,
    unsigned short* __restrict__ wt2)
{
  __shared__ PrepSh sh;
  const int tid = threadIdx.x;
  int id = blockIdx.x;
  if (id < 256){
    const int bq = id & 127, half = id >> 7;
    const int b = bq >> 5, qt = bq & 31;
    const int* base = mask + (size_t)b*2048*2048 + (size_t)(qt*64 + (tid>>4)*4)*2048 + (tid&15)*4;
    unsigned bits = 0;
    for (int i = 0; i < 16; ++i){
      const int* p = base + (half*16 + i)*64;
      int ok = 1;
      #pragma unroll
      for (int r = 0; r < 4; ++r){
        int4 v = *reinterpret_cast<const int4*>(p + (size_t)r*2048);
        ok &= (v.x!=0)&(v.y!=0)&(v.z!=0)&(v.w!=0);
      }
      bits |= (unsigned)ok << i;
    }
    #pragma unroll
    for (int o = 1; o < 64; o <<= 1) bits &= __shfl_xor(bits, o);
    if ((tid & 63) == 0) sh.red[tid >> 6] = bits;
    __syncthreads();
    if (tid == 0) mb16[bq*2 + half] = (unsigned short)(sh.red[0]&sh.red[1]&sh.red[2]&sh.red[3]);
    return;
  }
  id -= 256;
  if (id < 4096){
    int i = id * 256 + tid;
    float4 v = reinterpret_cast<const float4*>(src)[i];
    us4 o = { f2bf(v.x), f2bf(v.y), f2bf(v.z), f2bf(v.w) };
    reinterpret_cast<us4*>(x_bf)[i] = o;
    return;
  }
  id -= 4096;
  if (id < 768){
    int z = id / 32, rem = id % 32, x = rem & 15, y = rem >> 4;
    int sel = z >> 3, h = z & 7;
    const float* in = (sel==0 ? qw : (sel==1 ? kw : vw)) + (size_t)h*512*64;
    unsigned short* o = wtqkv + ((size_t)(sel*512 + h*64)) * 512;
    wtrans_body(in, o, 512, 64, x*32, y*32, tid, sh.t);
    return;
  }
  id -= 768;
  if (id < 6){
    int n = id*256 + tid;
    if (n < 1536){ int sel = n >> 9, r = n & 511;
      bqkv[n] = (sel==0 ? qb : (sel==1 ? kb : vb))[r]; }
    return;
  }
  id -= 6;
  if (id < 256){
    wtrans_body(ow, wto, 512, 512, (id & 15)*32, (id >> 4)*32, tid, sh.t);
    return;
  }
  id -= 256;
  if (id < 1024){
    wtrans_body(w1, wt1, 512, 2048, (id & 15)*32, (id >> 4)*32, tid, sh.t);
    return;
  }
  id -= 1024;
  wtrans_body(w2, wt2, 2048, 512, (id & 63)*32, (id >> 6)*32, tid, sh.t);
}

// ---------- GEMM: BK=64, per-row XOR swizzle; SPLIT=1 -> split-K in block ----------
// SPLIT=1: 512 thr / 8 waves; waves 0-3 K-half 0, waves 4-7 K-half 1; LDS-reduce.
// MODE 0: QKV scatter; 1: of = acc+bias+resid(f32); 2: ob0 = bf16 relu;
// MODE 3: of = acc+bias+bf2f(ob1[resid])
template<int MODE, int SPLIT>
__global__ __launch_bounds__(SPLIT ? 512 : 256, SPLIT ? 2 : 3) void k_gemm(
    const unsigned short* __restrict__ A, const unsigned short* __restrict__ Bt,
    const float* __restrict__ bias, const float* __restrict__ resid,
    unsigned short* __restrict__ ob0, const unsigned short* __restrict__ ob1,
    unsigned short* __restrict__ ob2,
    float* __restrict__ of, int M, int N, int K)
{
  constexpr int NG = SPLIT ? 2 : 1;
  __shared__ unsigned short As[NG][128*64];
  __shared__ unsigned short Bs[NG][128*64];
  const int tid = threadIdx.x, lane = tid & 63, wid = tid >> 6;
  const int w4 = wid & 3, kh = SPLIT ? (wid >> 2) : 0;
  const int g = lane >> 4, lr = lane & 15;
  const int rowBase = blockIdx.x * 128, colBase = blockIdx.y * 128;
  const int wr = (w4 >> 1) * 64, wc = (w4 & 1) * 64;
  const int srow8 = lane >> 3;
  const int schunk = (lane & 7) ^ (srow8 & 7);
  const int Keff = SPLIT ? (K >> 1) : K;
  const unsigned short* pA = A + (size_t)(rowBase + w4*32 + srow8)*K + kh*Keff + schunk*8;
  const unsigned short* pB = Bt + (size_t)(colBase + w4*32 + srow8)*K + kh*Keff + schunk*8;
  f32x4 acc[4][4] = {};
  for (int k0 = 0; k0 < Keff; k0 += 64){
    __syncthreads();
    #pragma unroll
    for (int t = 0; t < 4; ++t){
      gl_lds16(pA + (size_t)(t*8)*K + k0, &As[kh][(w4*32 + t*8)*64]);
      gl_lds16(pB + (size_t)(t*8)*K + k0, &Bs[kh][(w4*32 + t*8)*64]);
    }
    __syncthreads();
    #pragma unroll
    for (int ks = 0; ks < 2; ++ks){
      const int rc = ((ks*4 + g) ^ (lr & 7)) * 8;
      bf16x8 af[4], bfr[4];
      #pragma unroll
      for (int mi = 0; mi < 4; ++mi) af[mi]  = *reinterpret_cast<const bf16x8*>(&As[kh][(wr + mi*16 + lr)*64 + rc]);
      #pragma unroll
      for (int ni = 0; ni < 4; ++ni) bfr[ni] = *reinterpret_cast<const bf16x8*>(&Bs[kh][(wc + ni*16 + lr)*64 + rc]);
      __builtin_amdgcn_s_setprio(1);
      #pragma unroll
      for (int mi = 0; mi < 4; ++mi)
        #pragma unroll
        for (int ni = 0; ni < 4; ++ni)
          acc[mi][ni] = __builtin_amdgcn_mfma_f32_16x16x32_bf16(af[mi], bfr[ni], acc[mi][ni], 0, 0, 0);
      __builtin_amdgcn_s_setprio(0);
    }
  }
  if constexpr (SPLIT){
    // cross-group reduce: high wave w+4's acc added into low wave w's acc.
    float* xb = (float*)&As[0][0];
    #pragma unroll
    for (int p = 0; p < 2; ++p){
      __syncthreads();
      if (kh == 1 && (w4 >> 1) == p){
        const int slot = w4 & 1;
        #pragma unroll
        for (int mi = 0; mi < 4; ++mi)
          #pragma unroll
          for (int ni = 0; ni < 4; ++ni)
            #pragma unroll
            for (int j = 0; j < 4; ++j)
              xb[slot*4096 + (mi*16 + ni*4 + j)*64 + lane] = acc[mi][ni][j];
      }
      __syncthreads();
      if (kh == 0 && (w4 >> 1) == p){
        const int slot = w4 & 1;
        #pragma unroll
        for (int mi = 0; mi < 4; ++mi)
          #pragma unroll
          for (int ni = 0; ni < 4; ++ni)
            #pragma unroll
            for (int j = 0; j < 4; ++j)
              acc[mi][ni][j] += xb[slot*4096 + (mi*16 + ni*4 + j)*64 + lane];
      }
    }
    if (kh == 1) return;   // high waves done (no barriers after this point)
  }
  float bv[4];
  #pragma unroll
  for (int ni = 0; ni < 4; ++ni) bv[ni] = bias[colBase + wc + ni*16 + lr];
  #pragma unroll
  for (int mi = 0; mi < 4; ++mi){
    #pragma unroll
    for (int ni = 0; ni < 4; ++ni){
      #pragma unroll
      for (int j = 0; j < 4; ++j){
        int m = rowBase + wr + mi*16 + g*4 + j;
        int n = colBase + wc + ni*16 + lr;
        float v = acc[mi][ni][j] + bv[ni];
        if constexpr (MODE == 0){
          int b = m >> 11, s = m & 2047;
          int sel = n >> 9, rr = n & 511, h = rr >> 6, e = rr & 63;
          size_t bh = (size_t)(b*8 + h);
          if (sel == 0)      ob0[(bh*2048 + s)*64 + e] = f2bf(v);
          else if (sel == 1) ((unsigned short*)ob1)[(bh*2048 + s)*64 + e] = f2bf(v);
          else               ob2[(bh*64 + e)*2048 + s] = f2bf(v);   // V transposed
        } else if constexpr (MODE == 1){
          of[(size_t)m*N + n] = v + resid[(size_t)m*N + n];
        } else if constexpr (MODE == 3){
          of[(size_t)m*N + n] = v + bf2f(ob1[(size_t)m*N + n]);
        } else {
          ob0[(size_t)m*N + n] = f2bf(v > 0.f ? v : 0.f);
        }
      }
    }
  }
}

// ---------- flash attention: KVBLK=128, 16 q/wave, 8 waves; MFMA l-sum ----------
__global__ __launch_bounds__(512) void k_attn(
    const unsigned short* __restrict__ Qb, const unsigned short* __restrict__ Kb,
    const unsigned short* __restrict__ Vt, const int* __restrict__ mask,
    const unsigned* __restrict__ mbits_p, unsigned short* __restrict__ ctx)
{
  __shared__ unsigned short Ks[2][8192];   // 128 x 64
  __shared__ unsigned short Vs[2][8192];   // 64 x 128
  const int tid = threadIdx.x, lane = tid & 63, wid = tid >> 6;   // wid 0..7
  const int g = lane >> 4, lr = lane & 15;
  const int qt = blockIdx.y, bh = blockIdx.x;   // bh fastest -> XCD locality
  const int b = bh >> 3, h = bh & 7;
  const int qw = qt * 128 + wid * 16;
  const unsigned mbits = mbits_p[b*32 + qt*2] & mbits_p[b*32 + qt*2 + 1];
  const size_t mbase = (size_t)b * 2048 * 2048;
  const float SC = 0.18033688f;   // log2(e)/sqrt(64)

  const int l8 = lane >> 3, l7 = lane & 7, l16 = lane >> 4, l15 = lane & 15;
  const unsigned short* kg0 = Kb + (size_t)bh*2048*64 + ((size_t)(wid*16) + l8)*64 + ((l7 ^ (l8 & 7)))*8;
  const int vrow0 = wid*8 + l16, vrow1 = wid*8 + 4 + l16;
  const unsigned short* vg0 = Vt + (size_t)bh*64*2048 + (size_t)vrow0*2048 + ((l15 ^ (vrow0 & 15)))*8;
  const unsigned short* vg1 = Vt + (size_t)bh*64*2048 + (size_t)vrow1*2048 + ((l15 ^ (vrow1 & 15)))*8;

  #define STAGE(buf, t) do { \
    gl_lds16(kg0 + (size_t)(t)*8192,       &Ks[buf][(wid*16)*64]);    \
    gl_lds16(kg0 + (size_t)(t)*8192 + 512, &Ks[buf][(wid*16+8)*64]);  \
    gl_lds16(vg0 + (size_t)(t)*128,        &Vs[buf][(wid*8)*128]);    \
    gl_lds16(vg1 + (size_t)(t)*128,        &Vs[buf][(wid*8+4)*128]);  \
  } while(0)

  STAGE(0, 0);

  bf16x8 b_q[2];   // Q as B-operand: col q = lr, k(e) = ks*32 + 8g + j
  {
    const unsigned short* qp = Qb + ((size_t)bh*2048 + qw + lr)*64;
    b_q[0] = *reinterpret_cast<const bf16x8*>(qp + g*8);
    b_q[1] = *reinterpret_cast<const bf16x8*>(qp + 32 + g*8);
  }
  const u32x4 ones_u = { 0x3f803f80u, 0x3f803f80u, 0x3f803f80u, 0x3f803f80u };
  const bf16x8 ones = __builtin_bit_cast(bf16x8, ones_u);   // all bf16 1.0
  f32x4 acc[4] = {};    // ctx^T frags: row e = ne*16+4g+j, col q = lr
  f32x4 acc_l = {};     // ones x P: every row = l partial for col q = lr
  float m_run = -3.0e38f;
  int cur = 0;
  __syncthreads();     // first tile staged (vmcnt drained by barrier semantics)

  for (int kt = 0; kt < 16; ++kt){
    if (kt < 15) STAGE(cur^1, kt+1);   // issue next-tile DMA; lands before end barrier
    const unsigned short* Kc = Ks[cur];
    const unsigned short* Vc = Vs[cur];
    // QK^T (swapped): A = K rows (k = mk*16+4g+j), B = Q (col q = lr)
    f32x4 st[8];
    #pragma unroll
    for (int mk = 0; mk < 8; ++mk) st[mk] = f32x4{0.f,0.f,0.f,0.f};
    __builtin_amdgcn_s_setprio(1);
    #pragma unroll
    for (int mk = 0; mk < 8; ++mk)
      #pragma unroll
      for (int ks = 0; ks < 2; ++ks){
        bf16x8 kf = *reinterpret_cast<const bf16x8*>(
            &Kc[(mk*16 + lr)*64 + (((ks*4 + g) ^ (lr & 7)))*8]);
        st[mk] = __builtin_amdgcn_mfma_f32_16x16x32_bf16(kf, b_q[ks], st[mk], 0,0,0);
      }
    __builtin_amdgcn_s_setprio(0);
    if (((mbits >> (kt*2)) & 3u) != 3u){
      const int kk0 = kt * 128;
      #pragma unroll
      for (int mk = 0; mk < 8; ++mk)
        #pragma unroll
        for (int j = 0; j < 4; ++j){
          int kg = kk0 + mk*16 + g*4 + j;
          if (mask[mbase + (size_t)(qw + lr)*2048 + kg] == 0) st[mk][j] = -3.0e30f;
        }
    }
    // online softmax (log2 domain); max tree over 32 values
    float pm[8];
    #pragma unroll
    for (int mk = 0; mk < 8; ++mk)
      pm[mk] = fmaxf(fmaxf(st[mk][0], st[mk][1]), fmaxf(st[mk][2], st[mk][3]));
    float tA = fmaxf(fmaxf(pm[0], pm[1]), fmaxf(pm[2], pm[3]));
    float tB = fmaxf(fmaxf(pm[4], pm[5]), fmaxf(pm[6], pm[7]));
    float tm = fmaxf(tA, tB);
    tm = fmaxf(tm, __shfl_xor(tm, 16));
    tm = fmaxf(tm, __shfl_xor(tm, 32));
    float tms = tm * SC;
    if (!__all(tms <= m_run + 8.f)){   // defer-max, THR=8 (P bounded by 2^8)
      float mnew = fmaxf(m_run, tms);
      float alpha = exp2_hw(m_run - mnew);
      #pragma unroll
      for (int ne = 0; ne < 4; ++ne)
        #pragma unroll
        for (int j = 0; j < 4; ++j) acc[ne][j] *= alpha;
      #pragma unroll
      for (int j = 0; j < 4; ++j) acc_l[j] *= alpha;
      m_run = mnew;
    }
    // P = 2^(S*SC - m_run); pack bf16; permlane -> PV B-frags
    unsigned wrd[8][2];
    #pragma unroll
    for (int mk = 0; mk < 8; ++mk){
      float p0 = exp2_hw(__builtin_fmaf(st[mk][0], SC, -m_run));
      float p1 = exp2_hw(__builtin_fmaf(st[mk][1], SC, -m_run));
      float p2 = exp2_hw(__builtin_fmaf(st[mk][2], SC, -m_run));
      float p3 = exp2_hw(__builtin_fmaf(st[mk][3], SC, -m_run));
      wrd[mk][0] = cvt_pk_bf16(p0, p1);
      wrd[mk][1] = cvt_pk_bf16(p2, p3);
    }
    bf16x8 pw[4];
    #pragma unroll
    for (int ks = 0; ks < 4; ++ks){
      unsigned a0w = wrd[2*ks][0], b0w = wrd[2*ks+1][0];
      unsigned a1w = wrd[2*ks][1], b1w = wrd[2*ks+1][1];
      plswap32(a0w, b0w); plswap16(a0w, b0w);
      plswap32(a1w, b1w); plswap16(a1w, b1w);
      u32x4 pk = { a0w, a1w, b0w, b1w };
      pw[ks] = __builtin_bit_cast(bf16x8, pk);
    }
    // PV: ctx^T += Vt * P^T ; l += ones * P^T (matrix pipe computes the denom)
    __builtin_amdgcn_s_setprio(1);
    #pragma unroll
    for (int ks = 0; ks < 4; ++ks){
      #pragma unroll
      for (int ne = 0; ne < 4; ++ne){
        bf16x8 vf = *reinterpret_cast<const bf16x8*>(
            &Vc[(ne*16 + lr)*128 + (((ks*4 + g) ^ lr))*8]);
        acc[ne] = __builtin_amdgcn_mfma_f32_16x16x32_bf16(vf, pw[ks], acc[ne], 0,0,0);
      }
      acc_l = __builtin_amdgcn_mfma_f32_16x16x32_bf16(ones, pw[ks], acc_l, 0,0,0);
    }
    __builtin_amdgcn_s_setprio(0);
    if (kt < 15){
      __syncthreads();   // drains next-tile DMA + orders buffer reuse
      cur ^= 1;
    }
  }
  #undef STAGE
  float inv = 1.f / acc_l[0];   // all rows of ones x P are identical
  int q = qw + lr;
  #pragma unroll
  for (int ne = 0; ne < 4; ++ne){
    uint2 ow;
    ow.x = cvt_pk_bf16(acc[ne][0]*inv, acc[ne][1]*inv);
    ow.y = cvt_pk_bf16(acc[ne][2]*inv, acc[ne][3]*inv);
    *reinterpret_cast<uint2*>(&ctx[((size_t)b*2048 + q)*512 + h*64 + ne*16 + g*4]) = ow;
  }
}

// ---------- LayerNorm: wave per row of 512; f32 out optional ----------
__global__ __launch_bounds__(256) void k_ln(
    const float* __restrict__ in, const float* __restrict__ gma, const float* __restrict__ bta,
    float* __restrict__ of, unsigned short* __restrict__ ob)
{
  const int lane = threadIdx.x & 63, wid = threadIdx.x >> 6;
  const size_t row = (size_t)blockIdx.x * 4 + wid;
  const float* x = in + row * 512;
  const int e0 = lane * 8;
  float xv[8];
  *reinterpret_cast<float4*>(&xv[0]) = *reinterpret_cast<const float4*>(x + e0);
  *reinterpret_cast<float4*>(&xv[4]) = *reinterpret_cast<const float4*>(x + e0 + 4);
  float s = 0.f, ss = 0.f;
  #pragma unroll
  for (int i = 0; i < 8; ++i){ s += xv[i]; ss += xv[i]*xv[i]; }
  #pragma unroll
  for (int o = 1; o < 64; o <<= 1){ s += __shfl_xor(s, o); ss += __shfl_xor(ss, o); }
  float mu = s * (1.f/512.f);
  float var = ss * (1.f/512.f) - mu*mu;
  float rs = rsqrtf(var + 1e-5f);
  float gv[8], bv[8], y[8];
  *reinterpret_cast<float4*>(&gv[0]) = *reinterpret_cast<const float4*>(gma + e0);
  *reinterpret_cast<float4*>(&gv[4]) = *reinterpret_cast<const float4*>(gma + e0 + 4);
  *reinterpret_cast<float4*>(&bv[0]) = *reinterpret_cast<const float4*>(bta + e0);
  *reinterpret_cast<float4*>(&bv[4]) = *reinterpret_cast<const float4*>(bta + e0 + 4);
  #pragma unroll
  for (int i = 0; i < 8; ++i) y[i] = (xv[i]-mu)*rs*gv[i] + bv[i];
  if (of){
    *reinterpret_cast<float4*>(of + row*512 + e0)     = *reinterpret_cast<float4*>(&y[0]);
    *reinterpret_cast<float4*>(of + row*512 + e0 + 4) = *reinterpret_cast<float4*>(&y[4]);
  }
  if (ob){
    us4 o0 = { f2bf(y[0]), f2bf(y[1]), f2bf(y[2]), f2bf(y[3]) };
    us4 o1 = { f2bf(y[4]), f2bf(y[5]), f2bf(y[6]), f2bf(y[7]) };
    *reinterpret_cast<us4*>(ob + row*512 + e0)     = o0;
    *reinterpret_cast<us4*>(ob + row*512 + e0 + 4) = o1;
  }
}

extern "C" void kernel_launch(void* const* d_in, const int* in_sizes, int n_in,
                              void* d_out, int out_size, void* d_ws, size_t ws_size,
                              hipStream_t stream)
{
  const float* src  = (const float*)d_in[0];
  const int*   mask = (const int*)d_in[1];
  const float* q_w  = (const float*)d_in[2];
  const float* q_b  = (const float*)d_in[3];
  const float* k_w  = (const float*)d_in[4];
  const float* k_b  = (const float*)d_in[5];
  const float* v_w  = (const float*)d_in[6];
  const float* v_b  = (const float*)d_in[7];
  const float* o_w  = (const float*)d_in[8];
  const float* o_b  = (const float*)d_in[9];
  const float* ln1g = (const float*)d_in[10];
  const float* ln1b = (const float*)d_in[11];
  const float* w1   = (const float*)d_in[12];
  const float* b1   = (const float*)d_in[13];
  const float* w2   = (const float*)d_in[14];
  const float* b2   = (const float*)d_in[15];
  const float* ln2g = (const float*)d_in[16];
  const float* ln2b = (const float*)d_in[17];

  char* ws = (char*)d_ws;
  if (ws_size < 81795072) return;
  unsigned short* x_bf  = (unsigned short*)(ws + 0);          // 8.4MB (reused as LN1 bf16 out)
  unsigned short* wtqkv = (unsigned short*)(ws + 8388608);
  float*          bqkv  = (float*)(ws + 9961472);
  unsigned short* wto   = (unsigned short*)(ws + 9967616);
  unsigned short* wt1   = (unsigned short*)(ws + 10491904);
  unsigned short* wt2   = (unsigned short*)(ws + 12589056);
  unsigned short* Qb    = (unsigned short*)(ws + 14686208);
  unsigned short* Kb    = (unsigned short*)(ws + 23074816);
  unsigned short* Vt    = (unsigned short*)(ws + 31463424);
  unsigned short* ctx   = (unsigned short*)(ws + 39852032);
  unsigned short* ffb   = (unsigned short*)(ws + 14686208);   // overlays Q/K/Vt/ctx (dead by FF1)
  float* res = (float*)(ws + 48240640);                        // res1 then res2
  unsigned short* mb16 = (unsigned short*)(ws + 48240640);     // bitmap in res head (dead by gemm<1>)
  const unsigned* mb32 = (const unsigned*)(ws + 48240640);
  float* outf = (float*)d_out;

  k_prep<<<7430, 256, 0, stream>>>(mask, src, q_w, k_w, v_w, q_b, k_b, v_b,
                                   o_w, w1, w2, mb16, x_bf, wtqkv, bqkv, wto, wt1, wt2);

  k_gemm<0,0><<<dim3(64,12), 256, 0, stream>>>(x_bf, wtqkv, bqkv, nullptr,
                                               Qb, Kb, Vt, nullptr, 8192, 1536, 512);
  k_attn<<<dim3(32,16), 512, 0, stream>>>(Qb, Kb, Vt, mask, mb32, ctx);
  k_gemm<1,1><<<dim3(64,4), 512, 0, stream>>>(ctx, wto, o_b, src,
                                              nullptr, nullptr, nullptr, res, 8192, 512, 512);
  k_ln<<<2048, 256, 0, stream>>>(res, ln1g, ln1b, nullptr, x_bf);   // bf16 only
  k_gemm<2,0><<<dim3(64,16), 256, 0, stream>>>(x_bf, wt1, b1, nullptr,
                                               ffb, nullptr, nullptr, nullptr, 8192, 2048, 512);
  k_gemm<3,1><<<dim3(64,4), 512, 0, stream>>>(ffb, wt2, b2, nullptr,
                                              nullptr, x_bf, nullptr, res, 8192, 512, 2048);
  k_ln<<<2048, 256, 0, stream>>>(res, ln2g, ln2b, outf, nullptr);
}